// Round 3
// baseline (482.892 us; speedup 1.0000x reference)
//
#include <hip/hip_runtime.h>
#include <hip/hip_bf16.h>

typedef float f32x4 __attribute__((ext_vector_type(4)));
typedef short s16x8 __attribute__((ext_vector_type(8)));

#define SIGC 2379
#define KPAD 2432
#define NPATH 12800
#define KSPLIT 4
#define KSEGLEN (KPAD / KSPLIT)   // 608 = 19 * 32

__device__ inline void split2(float v, __hip_bfloat16* h, __hip_bfloat16* l) {
    __hip_bfloat16 hh = __float2bfloat16(v);
    *h = hh;
    *l = __float2bfloat16(v - __bfloat162float(hh));
}

__device__ inline void gload_lds16(const void* g, void* l) {
    __builtin_amdgcn_global_load_lds(
        (const __attribute__((address_space(1))) void*)g,
        (__attribute__((address_space(3))) void*)l,
        16, 0, 0);
}

// ---------------------------------------------------------------------------
// W convert: W[256][2379] fp32 -> Wh/Wl[256][2432] bf16 hi+lo (pad zeroed)
// ---------------------------------------------------------------------------
__global__ __launch_bounds__(256) void wconv_kernel(const float* __restrict__ W,
                                                    __hip_bfloat16* __restrict__ Wh,
                                                    __hip_bfloat16* __restrict__ Wl)
{
    int k = blockIdx.x * 256 + threadIdx.x;
    int n = blockIdx.y;
    if (k < KPAD) {
        float v = (k < SIGC) ? W[(size_t)n * SIGC + k] : 0.0f;
        split2(v, &Wh[(size_t)n * KPAD + k], &Wl[(size_t)n * KPAD + k]);
    }
}

// ---------------------------------------------------------------------------
// out init: out[n][o][i][j] = b[o]   (float4 granularity; 400 float4 per o)
// ---------------------------------------------------------------------------
__global__ __launch_bounds__(256) void binit_kernel(const float* __restrict__ b,
                                                    float4* __restrict__ out4)
{
    int i4 = blockIdx.x * 256 + threadIdx.x;   // 819200 total
    int o = (i4 / 400) & 255;
    float bo = b[o];
    out4[i4] = make_float4(bo, bo, bo, bo);
}

// ---------------------------------------------------------------------------
// Signature kernel: one wave per path (4 paths/wave, 16/block).
// Register-only Chen scan; lane owns pairs p in {lane, lane+64, lane+128(<169)}.
// s3[ijk] += dx[k] * (s2[ij] + 0.5*dx[j]*(s1[i] + dx[i]/3))
// Output staged in LDS, copied out with coalesced int4 stores.
// ---------------------------------------------------------------------------
__global__ __launch_bounds__(256) void sig_kernel(const float* __restrict__ x,
                                                  __hip_bfloat16* __restrict__ Ah,
                                                  __hip_bfloat16* __restrict__ Al_,
                                                  int r_start)
{
    __shared__ float inc_s[4][5][16];            // [wave][step][channel]
    __shared__ __hip_bfloat16 hi_s[4][KPAD];     // per-wave sig row (hi)
    __shared__ __hip_bfloat16 lo_s[4][KPAD];     // per-wave sig row (lo)

    const int t = threadIdx.x;
    const int w = t >> 6;
    const int lane = t & 63;

    const int p0 = lane;
    const int p1 = lane + 64;
    const int p2 = lane + 128;
    const bool has2 = (p2 < 169);
    const int i0 = p0 / 13, j0 = p0 - i0 * 13;
    const int i1 = p1 / 13, j1 = p1 - i1 * 13;
    const int i2 = p2 / 13, j2 = p2 - i2 * 13;   // used under has2
    (void)j0; (void)j1; (void)j2;

    for (int pp = 0; pp < 4; ++pp) {
        const int r = r_start + blockIdx.x * 16 + w * 4 + pp;
        const int nn = r & 7;
        const int jj = (r >> 3) & 63;
        const int ii = r >> 9;

        __syncthreads();   // inc_s + hi_s/lo_s reuse guard across pp
        if (lane < 13) {
            if (lane < 12) {
                const float* px = x + ((size_t)(nn * 12 + lane) * 1600 + ii * 64 + jj) * 5;
                float prev = 0.0f;
                #pragma unroll
                for (int l = 0; l < 5; ++l) {
                    float v = px[l];
                    inc_s[w][l][lane] = v - prev;
                    prev = v;
                }
            } else {
                inc_s[w][0][12] = 0.0f;
                #pragma unroll
                for (int l = 1; l < 5; ++l) inc_s[w][l][12] = 0.25f;
            }
        }
        __syncthreads();

        float s1i0 = 0.0f, s1i1 = 0.0f, s1i2 = 0.0f;
        float s2p0 = 0.0f, s2p1 = 0.0f, s2p2 = 0.0f;
        float s1own = 0.0f;
        float s3a[13], s3b[13], s3c[13];
        #pragma unroll
        for (int k = 0; k < 13; ++k) { s3a[k] = 0.0f; s3b[k] = 0.0f; s3c[k] = 0.0f; }

        for (int l = 0; l < 5; ++l) {
            float dxl[13];
            #pragma unroll
            for (int k = 0; k < 13; ++k) dxl[k] = inc_s[w][l][k];

            {   // pair 0
                float dxi = inc_s[w][l][i0];
                float dxj = inc_s[w][l][j0];
                float C   = s2p0 + 0.5f * dxj * (s1i0 + dxi * (1.0f / 3.0f));
                #pragma unroll
                for (int k = 0; k < 13; ++k) s3a[k] += dxl[k] * C;
                s2p0 += s1i0 * dxj + 0.5f * dxi * dxj;
                s1i0 += dxi;
            }
            {   // pair 1
                float dxi = inc_s[w][l][i1];
                float dxj = inc_s[w][l][j1];
                float C   = s2p1 + 0.5f * dxj * (s1i1 + dxi * (1.0f / 3.0f));
                #pragma unroll
                for (int k = 0; k < 13; ++k) s3b[k] += dxl[k] * C;
                s2p1 += s1i1 * dxj + 0.5f * dxi * dxj;
                s1i1 += dxi;
            }
            if (has2) {   // pair 2
                float dxi = inc_s[w][l][i2];
                float dxj = inc_s[w][l][j2];
                float C   = s2p2 + 0.5f * dxj * (s1i2 + dxi * (1.0f / 3.0f));
                #pragma unroll
                for (int k = 0; k < 13; ++k) s3c[k] += dxl[k] * C;
                s2p2 += s1i2 * dxj + 0.5f * dxi * dxj;
                s1i2 += dxi;
            }
            if (lane < 13) s1own += inc_s[w][l][lane];
        }

        // ---- write sig row into LDS (hi/lo) ----
        if (lane < 13) split2(s1own, &hi_s[w][lane], &lo_s[w][lane]);
        split2(s2p0, &hi_s[w][13 + p0], &lo_s[w][13 + p0]);
        split2(s2p1, &hi_s[w][13 + p1], &lo_s[w][13 + p1]);
        if (has2) split2(s2p2, &hi_s[w][13 + p2], &lo_s[w][13 + p2]);
        #pragma unroll
        for (int k = 0; k < 13; ++k) split2(s3a[k], &hi_s[w][182 + p0 * 13 + k], &lo_s[w][182 + p0 * 13 + k]);
        #pragma unroll
        for (int k = 0; k < 13; ++k) split2(s3b[k], &hi_s[w][182 + p1 * 13 + k], &lo_s[w][182 + p1 * 13 + k]);
        if (has2) {
            #pragma unroll
            for (int k = 0; k < 13; ++k) split2(s3c[k], &hi_s[w][182 + p2 * 13 + k], &lo_s[w][182 + p2 * 13 + k]);
        }
        if (lane < KPAD - SIGC) {   // zero pad 2379..2431 (53 elems)
            hi_s[w][SIGC + lane] = __float2bfloat16(0.0f);
            lo_s[w][SIGC + lane] = __float2bfloat16(0.0f);
        }

        __syncthreads();   // ensure LDS rows complete (incl. cross-lane) before copy

        // ---- coalesced copy out: 304 int4 per array ----
        const int4* sh = (const int4*)&hi_s[w][0];
        const int4* sl = (const int4*)&lo_s[w][0];
        int4* dh = (int4*)(Ah + (size_t)(r - r_start) * KPAD);
        int4* dl = (int4*)(Al_ + (size_t)(r - r_start) * KPAD);
        for (int i = lane; i < KPAD * 2 / 16; i += 64) {
            dh[i] = sh[i];
            dl[i] = sl[i];
        }
    }
}

// ---------------------------------------------------------------------------
// Split-bf16 GEMM with split-K=4:
// D[m][o] += sum_{k in seg} Ah*Wh + Ah*Wl + Al*Wh   (atomicAdd, bias pre-init)
// 128x128 tile, 4 waves 2x2 (each 64x64 = 4x4 frags of 16x16x32 bf16).
// LDS: kseg-major [array][kseg][row][8] staged via global_load_lds (wave w
// owns array w; dest is wave-linear base + lane*16 = row-linear). Frag reads
// are 256B-contiguous per 16-lane group -> conflict-free.
// ---------------------------------------------------------------------------
__global__ __launch_bounds__(256) void gemm_kernel(const __hip_bfloat16* __restrict__ Ah,
                                                   const __hip_bfloat16* __restrict__ Al_,
                                                   const __hip_bfloat16* __restrict__ Wh,
                                                   const __hip_bfloat16* __restrict__ Wl,
                                                   float* __restrict__ out,
                                                   int r_start)
{
    __shared__ __hip_bfloat16 L[4][4096];   // [array][kseg*1024 + row*8], 8KB each

    const int t = threadIdx.x;
    const int lane = t & 63;
    const int w = t >> 6;
    const int wm = w >> 1, wn = w & 1;
    const int m0 = blockIdx.y * 128;
    const int n0 = blockIdx.x * 128;
    const int k_base = blockIdx.z * KSEGLEN;

    // wave w stages array w: 0=Ah 1=Al 2=Wh 3=Wl
    const __hip_bfloat16* gptr = (w == 0) ? Ah : (w == 1) ? Al_ : (w == 2) ? Wh : Wl;
    const int row0 = (w < 2) ? m0 : n0;
    gptr += (size_t)(row0 + lane) * KPAD + k_base;

    f32x4 acc[4][4] = {};

    for (int kk = 0; kk < KSEGLEN; kk += 32) {
        __syncthreads();   // previous compute done before overwrite
        #pragma unroll
        for (int c = 0; c < 4; ++c) {
            #pragma unroll
            for (int h = 0; h < 2; ++h) {
                gload_lds16(gptr + (size_t)h * 64 * KPAD + kk + c * 8,
                            &L[w][(c * 128 + h * 64) * 8]);
            }
        }
        __syncthreads();   // compiler drains vmcnt before barrier

        s16x8 ah[4], al4[4], bh[4], bl4[4];
        #pragma unroll
        for (int m = 0; m < 4; ++m) {
            int lo = ((lane >> 4) * 128 + wm * 64 + m * 16 + (lane & 15)) * 8;
            ah[m]  = *reinterpret_cast<const s16x8*>(&L[0][lo]);
            al4[m] = *reinterpret_cast<const s16x8*>(&L[1][lo]);
        }
        #pragma unroll
        for (int n = 0; n < 4; ++n) {
            int lo = ((lane >> 4) * 128 + wn * 64 + n * 16 + (lane & 15)) * 8;
            bh[n]  = *reinterpret_cast<const s16x8*>(&L[2][lo]);
            bl4[n] = *reinterpret_cast<const s16x8*>(&L[3][lo]);
        }

        #pragma unroll
        for (int m = 0; m < 4; ++m)
            #pragma unroll
            for (int n = 0; n < 4; ++n) {
                acc[m][n] = __builtin_amdgcn_mfma_f32_16x16x32_bf16(ah[m],  bh[n],  acc[m][n], 0, 0, 0);
                acc[m][n] = __builtin_amdgcn_mfma_f32_16x16x32_bf16(ah[m],  bl4[n], acc[m][n], 0, 0, 0);
                acc[m][n] = __builtin_amdgcn_mfma_f32_16x16x32_bf16(al4[m], bh[n],  acc[m][n], 0, 0, 0);
            }
    }

    // epilogue: atomic accumulate (C/D layout: col=lane&15, row=(lane>>4)*4+reg)
    #pragma unroll
    for (int m = 0; m < 4; ++m) {
        int prow_base = m0 + wm * 64 + m * 16 + ((lane >> 4) << 2);
        #pragma unroll
        for (int n = 0; n < 4; ++n) {
            int o = n0 + wn * 64 + n * 16 + (lane & 15);
            #pragma unroll
            for (int rr = 0; rr < 4; ++rr) {
                int path = r_start + prow_base + rr;
                int ni = path & 7;
                int jj = (path >> 3) & 63;
                int ii = path >> 9;
                atomicAdd(&out[(size_t)(ni * 256 + o) * 1600 + ii * 64 + jj], acc[m][n][rr]);
            }
        }
    }
}

// ---------------------------------------------------------------------------
extern "C" void kernel_launch(void* const* d_in, const int* in_sizes, int n_in,
                              void* d_out, int out_size, void* d_ws, size_t ws_size,
                              hipStream_t stream)
{
    const float* x = (const float*)d_in[0];
    const float* W = (const float*)d_in[1];
    const float* b = (const float*)d_in[2];
    float* out = (float*)d_out;

    char* ws = (char*)d_ws;
    __hip_bfloat16* Wh = (__hip_bfloat16*)ws;
    __hip_bfloat16* Wl = Wh + (size_t)256 * KPAD;
    size_t a_off = (((size_t)256 * KPAD * 2 * 2) + 255) & ~(size_t)255;

    size_t avail = (ws_size > a_off) ? ws_size - a_off : 0;
    long long maxp = (long long)(avail / ((size_t)KPAD * 2 * 2));
    int chunk = (int)((maxp / 128) * 128);
    if (chunk > NPATH) chunk = NPATH;
    if (chunk < 128) chunk = 128;   // assume ws is at least ~4 MB

    __hip_bfloat16* Ah = (__hip_bfloat16*)(ws + a_off);
    __hip_bfloat16* Al_ = Ah + (size_t)chunk * KPAD;

    wconv_kernel<<<dim3(10, 256), 256, 0, stream>>>(W, Wh, Wl);
    binit_kernel<<<dim3(3200), 256, 0, stream>>>(b, (float4*)out);

    for (int r0 = 0; r0 < NPATH; r0 += chunk) {
        int cnt = NPATH - r0;
        if (cnt > chunk) cnt = chunk;
        sig_kernel<<<dim3(cnt / 16), 256, 0, stream>>>(x, Ah, Al_, r0);
        gemm_kernel<<<dim3(2, cnt / 128, KSPLIT), 256, 0, stream>>>(Ah, Al_, Wh, Wl, out, r0);
    }
}

// Round 4
// 168.103 us; speedup vs baseline: 2.8726x; 2.8726x over previous
//
#include <hip/hip_runtime.h>
#include <hip/hip_bf16.h>

typedef float f32x4 __attribute__((ext_vector_type(4)));
typedef short s16x8 __attribute__((ext_vector_type(8)));

#define SIGC 2379
#define KPAD 2432
#define NKT  76          // KPAD/32 k-tiles
#define NPATH 12800

// Tiled layout for A and W (bf16): element (row r, k) lives at
//   ((r>>4)*NKT + (k>>5))*512 + ((k>>3)&3)*128 + (r&15)*8 + (k&7)
// i.e. 1KB tiles of [ks(4)][R(16)][kw(8)] — fragment-ready for 16x16x32 MFMA
// and loadable with a single lane-linear global_load_lds per tile.

__device__ inline void split2(float v, __hip_bfloat16* h, __hip_bfloat16* l) {
    __hip_bfloat16 hh = __float2bfloat16(v);
    *h = hh;
    *l = __float2bfloat16(v - __bfloat162float(hh));
}

__device__ inline void gload_lds16(const __hip_bfloat16* g, __hip_bfloat16* l) {
    __builtin_amdgcn_global_load_lds(
        (const __attribute__((address_space(1))) void*)g,
        (__attribute__((address_space(3))) void*)l,
        16, 0, 0);
}

// ---------------------------------------------------------------------------
// W convert: W[256][2379] fp32 -> tiled Wh/Wl bf16 hi+lo (pad zeroed)
// ---------------------------------------------------------------------------
__global__ __launch_bounds__(256) void wconv_kernel(const float* __restrict__ W,
                                                    __hip_bfloat16* __restrict__ Wh,
                                                    __hip_bfloat16* __restrict__ Wl)
{
    int k = blockIdx.x * 256 + threadIdx.x;
    int n = blockIdx.y;
    if (k >= KPAD) return;
    float v = (k < SIGC) ? W[(size_t)n * SIGC + k] : 0.0f;
    size_t off = ((size_t)(n >> 4) * NKT + (k >> 5)) * 512 + ((k >> 3) & 3) * 128 + (n & 15) * 8 + (k & 7);
    split2(v, &Wh[off], &Wl[off]);
}

// ---------------------------------------------------------------------------
// Signature kernel: one wave per path (4 paths/wave, 16/block = one row-tile).
// Register-only Chen scan; lane owns pairs p in {lane, lane+64, lane+128(<169)}.
// s3[ijk] += dx[k] * (s2[ij] + 0.5*dx[j]*(s1[i] + dx[i]/3))
// Output staged in LDS, then written in tiled layout (16B chunks).
// ---------------------------------------------------------------------------
__global__ __launch_bounds__(256) void sig_kernel(const float* __restrict__ x,
                                                  __hip_bfloat16* __restrict__ Ah,
                                                  __hip_bfloat16* __restrict__ Al_,
                                                  int r_start)
{
    __shared__ float inc_s[4][5][16];                        // [wave][step][channel]
    __shared__ __align__(16) __hip_bfloat16 hi_s[4][KPAD];   // per-wave sig row (hi)
    __shared__ __align__(16) __hip_bfloat16 lo_s[4][KPAD];   // per-wave sig row (lo)

    const int t = threadIdx.x;
    const int w = t >> 6;
    const int lane = t & 63;

    const int p0 = lane;
    const int p1 = lane + 64;
    const int p2 = lane + 128;
    const bool has2 = (p2 < 169);
    const int i0 = p0 / 13, j0 = p0 - i0 * 13;
    const int i1 = p1 / 13, j1 = p1 - i1 * 13;
    const int i2 = p2 / 13, j2 = p2 - i2 * 13;   // used under has2

    for (int pp = 0; pp < 4; ++pp) {
        const int r = r_start + blockIdx.x * 16 + w * 4 + pp;
        const int nn = r & 7;
        const int jj = (r >> 3) & 63;
        const int ii = r >> 9;

        __syncthreads();   // guard inc_s / hi_s / lo_s reuse across pp
        if (lane < 13) {
            if (lane < 12) {
                const float* px = x + ((size_t)(nn * 12 + lane) * 1600 + ii * 64 + jj) * 5;
                float prev = 0.0f;
                #pragma unroll
                for (int l = 0; l < 5; ++l) {
                    float v = px[l];
                    inc_s[w][l][lane] = v - prev;
                    prev = v;
                }
            } else {
                inc_s[w][0][12] = 0.0f;
                #pragma unroll
                for (int l = 1; l < 5; ++l) inc_s[w][l][12] = 0.25f;
            }
        }
        __syncthreads();

        float s1i0 = 0.0f, s1i1 = 0.0f, s1i2 = 0.0f;
        float s2p0 = 0.0f, s2p1 = 0.0f, s2p2 = 0.0f;
        float s1own = 0.0f;
        float s3a[13], s3b[13], s3c[13];
        #pragma unroll
        for (int k = 0; k < 13; ++k) { s3a[k] = 0.0f; s3b[k] = 0.0f; s3c[k] = 0.0f; }

        for (int l = 0; l < 5; ++l) {
            float dxl[13];
            #pragma unroll
            for (int k = 0; k < 13; ++k) dxl[k] = inc_s[w][l][k];

            {   // pair 0
                float dxi = inc_s[w][l][i0];
                float dxj = inc_s[w][l][j0];
                float C   = s2p0 + 0.5f * dxj * (s1i0 + dxi * (1.0f / 3.0f));
                #pragma unroll
                for (int k = 0; k < 13; ++k) s3a[k] += dxl[k] * C;
                s2p0 += s1i0 * dxj + 0.5f * dxi * dxj;
                s1i0 += dxi;
            }
            {   // pair 1
                float dxi = inc_s[w][l][i1];
                float dxj = inc_s[w][l][j1];
                float C   = s2p1 + 0.5f * dxj * (s1i1 + dxi * (1.0f / 3.0f));
                #pragma unroll
                for (int k = 0; k < 13; ++k) s3b[k] += dxl[k] * C;
                s2p1 += s1i1 * dxj + 0.5f * dxi * dxj;
                s1i1 += dxi;
            }
            if (has2) {   // pair 2
                float dxi = inc_s[w][l][i2];
                float dxj = inc_s[w][l][j2];
                float C   = s2p2 + 0.5f * dxj * (s1i2 + dxi * (1.0f / 3.0f));
                #pragma unroll
                for (int k = 0; k < 13; ++k) s3c[k] += dxl[k] * C;
                s2p2 += s1i2 * dxj + 0.5f * dxi * dxj;
                s1i2 += dxi;
            }
            if (lane < 13) s1own += inc_s[w][l][lane];
        }

        // ---- write sig row into LDS (hi/lo) ----
        if (lane < 13) split2(s1own, &hi_s[w][lane], &lo_s[w][lane]);
        split2(s2p0, &hi_s[w][13 + p0], &lo_s[w][13 + p0]);
        split2(s2p1, &hi_s[w][13 + p1], &lo_s[w][13 + p1]);
        if (has2) split2(s2p2, &hi_s[w][13 + p2], &lo_s[w][13 + p2]);
        #pragma unroll
        for (int k = 0; k < 13; ++k) split2(s3a[k], &hi_s[w][182 + p0 * 13 + k], &lo_s[w][182 + p0 * 13 + k]);
        #pragma unroll
        for (int k = 0; k < 13; ++k) split2(s3b[k], &hi_s[w][182 + p1 * 13 + k], &lo_s[w][182 + p1 * 13 + k]);
        if (has2) {
            #pragma unroll
            for (int k = 0; k < 13; ++k) split2(s3c[k], &hi_s[w][182 + p2 * 13 + k], &lo_s[w][182 + p2 * 13 + k]);
        }
        if (lane < KPAD - SIGC) {   // zero pad 2379..2431 (53 elems)
            hi_s[w][SIGC + lane] = __float2bfloat16(0.0f);
            lo_s[w][SIGC + lane] = __float2bfloat16(0.0f);
        }

        __syncthreads();   // cross-lane LDS visibility before copy-out

        // ---- copy out in tiled layout: chunk i = elements 8i..8i+7 of the row ----
        const int rl = r - r_start;
        const int rtl = rl >> 4, R = rl & 15;
        const int4* sh = (const int4*)&hi_s[w][0];
        const int4* sl = (const int4*)&lo_s[w][0];
        for (int i = lane; i < KPAD / 8; i += 64) {
            size_t off = ((size_t)rtl * NKT + (i >> 2)) * 512 + (i & 3) * 128 + R * 8;
            *reinterpret_cast<int4*>(Ah + off)  = sh[i];
            *reinterpret_cast<int4*>(Al_ + off) = sl[i];
        }
    }
}

// ---------------------------------------------------------------------------
// Split-bf16 GEMM: D[m][o] = bias[o] + sum_k (Ah*Wh + Ah*Wl + Al*Wh).
// BM=64, BN=128 tiles, 4 waves as 2m x 2n (each 32x64 = 2x4 frags 16x16x32).
// Double-buffered LDS; each K-step stages 24 x 1KB tiles via lane-linear
// global_load_lds (wave w stages tiles 6w..6w+5). Epilogue: LDS transpose
// -> coalesced float4 stores with fused bias.
// ---------------------------------------------------------------------------
__global__ __launch_bounds__(256) void gemm_kernel(const __hip_bfloat16* __restrict__ Ah,
                                                   const __hip_bfloat16* __restrict__ Al_,
                                                   const __hip_bfloat16* __restrict__ Wh,
                                                   const __hip_bfloat16* __restrict__ Wl,
                                                   const float* __restrict__ b,
                                                   float* __restrict__ out,
                                                   int r_start)
{
    // LDS tile stack per buffer: [Ah:0-3 | Al:4-7 | Wh:8-15 | Wl:16-23] * 512 elem
    __shared__ __align__(16) __hip_bfloat16 L[2][24 * 512];   // 48 KB

    const int t = threadIdx.x;
    const int lane = t & 63;
    const int w = t >> 6;
    const int wm = w >> 1, wn = w & 1;
    const int n0 = blockIdx.x * 128;
    const int rt0 = blockIdx.y * 4;      // 4 m-tiles (chunk-local)
    const int nt0 = blockIdx.x * 8;      // 8 n-tiles

    f32x4 acc[2][4] = {};

    auto stage = [&](int buf, int kt) {
        #pragma unroll
        for (int s = 0; s < 6; ++s) {
            int tt = w * 6 + s;
            const __hip_bfloat16* g;
            if (tt < 4)       g = Ah  + ((size_t)(rt0 + tt)      * NKT + kt) * 512;
            else if (tt < 8)  g = Al_ + ((size_t)(rt0 + tt - 4)  * NKT + kt) * 512;
            else if (tt < 16) g = Wh  + ((size_t)(nt0 + tt - 8)  * NKT + kt) * 512;
            else              g = Wl  + ((size_t)(nt0 + tt - 16) * NKT + kt) * 512;
            gload_lds16(g + lane * 8, &L[buf][tt * 512]);
        }
    };

    stage(0, 0);
    int cur = 0;
    __syncthreads();

    for (int kt = 0; kt < NKT; ++kt) {
        if (kt + 1 < NKT) stage(cur ^ 1, kt + 1);   // issue-early prefetch

        const int fb = (lane >> 4) * 128 + (lane & 15) * 8;
        s16x8 ah[2], al4[2], bh[4], bl4[4];
        #pragma unroll
        for (int mm = 0; mm < 2; ++mm) {
            int base = (2 * wm + mm) * 512 + fb;
            ah[mm]  = *reinterpret_cast<const s16x8*>(&L[cur][base]);
            al4[mm] = *reinterpret_cast<const s16x8*>(&L[cur][2048 + base]);
        }
        #pragma unroll
        for (int nnn = 0; nnn < 4; ++nnn) {
            int base = (4 * wn + nnn) * 512 + fb;
            bh[nnn]  = *reinterpret_cast<const s16x8*>(&L[cur][4096 + base]);
            bl4[nnn] = *reinterpret_cast<const s16x8*>(&L[cur][8192 + base]);
        }

        #pragma unroll
        for (int mm = 0; mm < 2; ++mm)
            #pragma unroll
            for (int nnn = 0; nnn < 4; ++nnn) {
                acc[mm][nnn] = __builtin_amdgcn_mfma_f32_16x16x32_bf16(ah[mm],  bh[nnn],  acc[mm][nnn], 0, 0, 0);
                acc[mm][nnn] = __builtin_amdgcn_mfma_f32_16x16x32_bf16(ah[mm],  bl4[nnn], acc[mm][nnn], 0, 0, 0);
                acc[mm][nnn] = __builtin_amdgcn_mfma_f32_16x16x32_bf16(al4[mm], bh[nnn],  acc[mm][nnn], 0, 0, 0);
            }

        __syncthreads();   // reads done + prefetch drained
        cur ^= 1;
    }

    // ---- epilogue: transpose through LDS, coalesced stores with bias ----
    float* T = (float*)&L[0][0];   // 64 x 132 floats = 33.8 KB (stride-pad vs conflicts)
    #pragma unroll
    for (int mm = 0; mm < 2; ++mm)
        #pragma unroll
        for (int nnn = 0; nnn < 4; ++nnn)
            #pragma unroll
            for (int rr = 0; rr < 4; ++rr) {
                int p = wm * 32 + mm * 16 + (lane >> 4) * 4 + rr;
                int o = wn * 64 + nnn * 16 + (lane & 15);
                T[p * 132 + o] = acc[mm][nnn][rr];
            }
    __syncthreads();

    const int pbase = r_start + blockIdx.y * 64;
    const int ii = pbase >> 9;
    const int jj0 = (pbase >> 3) & 63;
    const int ol = t >> 1, hh = t & 1;
    const int o = n0 + ol;
    const float bo = b[o];
    #pragma unroll
    for (int c = 0; c < 4; ++c) {
        int ni = hh * 4 + c;
        float v[8];
        #pragma unroll
        for (int q = 0; q < 8; ++q) v[q] = T[(q * 8 + ni) * 132 + ol] + bo;
        float* dst = out + (size_t)(ni * 256 + o) * 1600 + ii * 64 + jj0;
        *reinterpret_cast<float4*>(dst)     = make_float4(v[0], v[1], v[2], v[3]);
        *reinterpret_cast<float4*>(dst + 4) = make_float4(v[4], v[5], v[6], v[7]);
    }
}

// ---------------------------------------------------------------------------
extern "C" void kernel_launch(void* const* d_in, const int* in_sizes, int n_in,
                              void* d_out, int out_size, void* d_ws, size_t ws_size,
                              hipStream_t stream)
{
    const float* x = (const float*)d_in[0];
    const float* W = (const float*)d_in[1];
    const float* b = (const float*)d_in[2];
    float* out = (float*)d_out;

    char* ws = (char*)d_ws;
    __hip_bfloat16* Wh = (__hip_bfloat16*)ws;
    __hip_bfloat16* Wl = Wh + (size_t)16 * NKT * 512;            // 622,592 elems each
    size_t a_off = (((size_t)16 * NKT * 512 * 2 * 2) + 255) & ~(size_t)255;

    size_t avail = (ws_size > a_off) ? ws_size - a_off : 0;
    long long maxp = (long long)(avail / ((size_t)KPAD * 2 * 2));
    int chunk = (int)((maxp / 128) * 128);
    if (chunk > NPATH) chunk = NPATH;
    if (chunk < 128) chunk = 128;   // assume ws is at least ~4 MB

    __hip_bfloat16* Ah = (__hip_bfloat16*)(ws + a_off);
    __hip_bfloat16* Al_ = Ah + (size_t)chunk * KPAD;

    wconv_kernel<<<dim3(10, 256), 256, 0, stream>>>(W, Wh, Wl);

    for (int r0 = 0; r0 < NPATH; r0 += chunk) {
        int cnt = NPATH - r0;
        if (cnt > chunk) cnt = chunk;
        sig_kernel<<<dim3(cnt / 16), 256, 0, stream>>>(x, Ah, Al_, r0);
        gemm_kernel<<<dim3(2, cnt / 64), 256, 0, stream>>>(Ah, Al_, Wh, Wl, b, out, r0);
    }
}

// Round 5
// 105.194 us; speedup vs baseline: 4.5905x; 1.5980x over previous
//
#include <hip/hip_runtime.h>
#include <hip/hip_bf16.h>

typedef float f32x4 __attribute__((ext_vector_type(4)));
typedef short s16x8 __attribute__((ext_vector_type(8)));

#define SIGC 2379
#define KPAD 2432
#define NKT  76          // KPAD/32 k-tiles
#define SROW 2440        // padded LDS row (16B-aligned, bank-skewed)
#define NPATH 12800

// Tiled layout for A and W (bf16): element (row r, k) lives at
//   ((r>>4)*NKT + (k>>5))*512 + ((k>>3)&3)*128 + (r&15)*8 + (k&7)
// i.e. 1KB tiles of [ks(4)][R(16)][kw(8)] — fragment-ready for 16x16x32 MFMA
// and loadable with a single lane-linear global_load_lds per tile.

__device__ inline void split2(float v, __hip_bfloat16* h, __hip_bfloat16* l) {
    __hip_bfloat16 hh = __float2bfloat16(v);
    *h = hh;
    *l = __float2bfloat16(v - __bfloat162float(hh));
}

__device__ inline void gload_lds16(const __hip_bfloat16* g, __hip_bfloat16* l) {
    __builtin_amdgcn_global_load_lds(
        (const __attribute__((address_space(1))) void*)g,
        (__attribute__((address_space(3))) void*)l,
        16, 0, 0);
}

// ---------------------------------------------------------------------------
// W convert: W[256][2379] fp32 -> tiled Wh/Wl bf16 hi+lo (pad zeroed)
// ---------------------------------------------------------------------------
__global__ __launch_bounds__(256) void wconv_kernel(const float* __restrict__ W,
                                                    __hip_bfloat16* __restrict__ Wh,
                                                    __hip_bfloat16* __restrict__ Wl)
{
    int k = blockIdx.x * 256 + threadIdx.x;
    int n = blockIdx.y;
    if (k >= KPAD) return;
    float v = (k < SIGC) ? W[(size_t)n * SIGC + k] : 0.0f;
    size_t off = ((size_t)(n >> 4) * NKT + (k >> 5)) * 512 + ((k >> 3) & 3) * 128 + (n & 15) * 8 + (k & 7);
    split2(v, &Wh[off], &Wl[off]);
}

// ---------------------------------------------------------------------------
// Signature kernel: 4 waves/block, 4 pp-phases; at phase pp wave w computes
// path row = pp*4 + w of the block's 16-row tile, so the 4 live rows are
// CONSECUTIVE -> block-cooperative copy-out in 64B-contiguous bursts.
// Register-only Chen scan; lane owns pairs p in {lane, lane+64, lane+128(<169)}.
// s3[ijk] += dx[k] * (s2[ij] + 0.5*dx[j]*(s1[i] + dx[i]/3))
// ---------------------------------------------------------------------------
__global__ __launch_bounds__(256) void sig_kernel(const float* __restrict__ x,
                                                  __hip_bfloat16* __restrict__ Ah,
                                                  __hip_bfloat16* __restrict__ Al_,
                                                  int r_start)
{
    __shared__ float inc_s[4][5][16];                        // [wave][step][channel]
    __shared__ __align__(16) __hip_bfloat16 hi_s[4][SROW];   // [wave] = row 4*pp+w
    __shared__ __align__(16) __hip_bfloat16 lo_s[4][SROW];

    const int t = threadIdx.x;
    const int w = t >> 6;
    const int lane = t & 63;

    const int p0 = lane;
    const int p1 = lane + 64;
    const int p2 = lane + 128;
    const bool has2 = (p2 < 169);
    const int i0 = p0 / 13, j0 = p0 - i0 * 13;
    const int i1 = p1 / 13, j1 = p1 - i1 * 13;
    const int i2 = p2 / 13, j2 = p2 - i2 * 13;   // used under has2

    for (int pp = 0; pp < 4; ++pp) {
        const int r = r_start + blockIdx.x * 16 + pp * 4 + w;
        const int nn = r & 7;
        const int jj = (r >> 3) & 63;
        const int ii = r >> 9;

        __syncthreads();   // guard inc_s / hi_s / lo_s reuse across pp
        if (lane < 13) {
            if (lane < 12) {
                const float* px = x + ((size_t)(nn * 12 + lane) * 1600 + ii * 64 + jj) * 5;
                float prev = 0.0f;
                #pragma unroll
                for (int l = 0; l < 5; ++l) {
                    float v = px[l];
                    inc_s[w][l][lane] = v - prev;
                    prev = v;
                }
            } else {
                inc_s[w][0][12] = 0.0f;
                #pragma unroll
                for (int l = 1; l < 5; ++l) inc_s[w][l][12] = 0.25f;
            }
        }
        __syncthreads();

        float s1i0 = 0.0f, s1i1 = 0.0f, s1i2 = 0.0f;
        float s2p0 = 0.0f, s2p1 = 0.0f, s2p2 = 0.0f;
        float s1own = 0.0f;
        float s3a[13], s3b[13], s3c[13];
        #pragma unroll
        for (int k = 0; k < 13; ++k) { s3a[k] = 0.0f; s3b[k] = 0.0f; s3c[k] = 0.0f; }

        for (int l = 0; l < 5; ++l) {
            float dxl[13];
            #pragma unroll
            for (int k = 0; k < 13; ++k) dxl[k] = inc_s[w][l][k];

            {   // pair 0
                float dxi = inc_s[w][l][i0];
                float dxj = inc_s[w][l][j0];
                float C   = s2p0 + 0.5f * dxj * (s1i0 + dxi * (1.0f / 3.0f));
                #pragma unroll
                for (int k = 0; k < 13; ++k) s3a[k] += dxl[k] * C;
                s2p0 += s1i0 * dxj + 0.5f * dxi * dxj;
                s1i0 += dxi;
            }
            {   // pair 1
                float dxi = inc_s[w][l][i1];
                float dxj = inc_s[w][l][j1];
                float C   = s2p1 + 0.5f * dxj * (s1i1 + dxi * (1.0f / 3.0f));
                #pragma unroll
                for (int k = 0; k < 13; ++k) s3b[k] += dxl[k] * C;
                s2p1 += s1i1 * dxj + 0.5f * dxi * dxj;
                s1i1 += dxi;
            }
            if (has2) {   // pair 2
                float dxi = inc_s[w][l][i2];
                float dxj = inc_s[w][l][j2];
                float C   = s2p2 + 0.5f * dxj * (s1i2 + dxi * (1.0f / 3.0f));
                #pragma unroll
                for (int k = 0; k < 13; ++k) s3c[k] += dxl[k] * C;
                s2p2 += s1i2 * dxj + 0.5f * dxi * dxj;
                s1i2 += dxi;
            }
            if (lane < 13) s1own += inc_s[w][l][lane];
        }

        // ---- write sig row into this wave's LDS row (hi/lo) ----
        if (lane < 13) split2(s1own, &hi_s[w][lane], &lo_s[w][lane]);
        split2(s2p0, &hi_s[w][13 + p0], &lo_s[w][13 + p0]);
        split2(s2p1, &hi_s[w][13 + p1], &lo_s[w][13 + p1]);
        if (has2) split2(s2p2, &hi_s[w][13 + p2], &lo_s[w][13 + p2]);
        #pragma unroll
        for (int k = 0; k < 13; ++k) split2(s3a[k], &hi_s[w][182 + p0 * 13 + k], &lo_s[w][182 + p0 * 13 + k]);
        #pragma unroll
        for (int k = 0; k < 13; ++k) split2(s3b[k], &hi_s[w][182 + p1 * 13 + k], &lo_s[w][182 + p1 * 13 + k]);
        if (has2) {
            #pragma unroll
            for (int k = 0; k < 13; ++k) split2(s3c[k], &hi_s[w][182 + p2 * 13 + k], &lo_s[w][182 + p2 * 13 + k]);
        }
        if (lane < KPAD - SIGC) {   // zero pad 2379..2431 (53 elems)
            hi_s[w][SIGC + lane] = __float2bfloat16(0.0f);
            lo_s[w][SIGC + lane] = __float2bfloat16(0.0f);
        }

        __syncthreads();   // all 4 rows complete before cooperative copy-out

        // ---- block-cooperative coalesced copy-out ----
        // thread t: rr=t&3 (row within quad), ks=(t>>2)&3, tile slot=t>>4.
        // threads 4q..4q+3 write 64B contiguous (rows 4pp..4pp+3, one ks).
        const int rtl = blockIdx.x;
        const int rr = t & 3, ks = (t >> 2) & 3, ts = t >> 4;
        #pragma unroll
        for (int it2 = 0; it2 < 5; ++it2) {
            int kt = it2 * 16 + ts;
            if (kt < NKT) {
                size_t off = ((size_t)rtl * NKT + kt) * 512 + ks * 128 + (pp * 4 + rr) * 8;
                int lidx = kt * 32 + ks * 8;
                *reinterpret_cast<int4*>(Ah + off)  = *reinterpret_cast<const int4*>(&hi_s[rr][lidx]);
                *reinterpret_cast<int4*>(Al_ + off) = *reinterpret_cast<const int4*>(&lo_s[rr][lidx]);
            }
        }
    }
}

// ---------------------------------------------------------------------------
// Split-bf16 GEMM: D[m][o] = bias[o] + sum_k (Ah*Wh + Ah*Wl + Al*Wh).
// BM=64, BN=128; 1D grid with XCD-pair swizzle: blocks (q*8+x8, h=0/1) share
// the A-tile and land on the same XCD slot -> A served from L2 on 2nd use.
// 4 waves as 2m x 2n; double-buffered LDS; 1KB-tile lane-linear
// global_load_lds staging; epilogue transposes via LDS -> float4 stores.
// ---------------------------------------------------------------------------
__global__ __launch_bounds__(256) void gemm_kernel(const __hip_bfloat16* __restrict__ Ah,
                                                   const __hip_bfloat16* __restrict__ Al_,
                                                   const __hip_bfloat16* __restrict__ Wh,
                                                   const __hip_bfloat16* __restrict__ Wl,
                                                   const float* __restrict__ b,
                                                   float* __restrict__ out,
                                                   int r_start, int nmblk)
{
    __shared__ __align__(16) __hip_bfloat16 L[2][24 * 512];   // 48 KB

    const int bid = blockIdx.x;
    const int x8 = bid & 7, h = (bid >> 3) & 1, q = bid >> 4;
    const int mIdx = q * 8 + x8;
    if (mIdx >= nmblk) return;

    const int t = threadIdx.x;
    const int lane = t & 63;
    const int w = t >> 6;
    const int wm = w >> 1, wn = w & 1;
    const int n0 = h * 128;
    const int rt0 = mIdx * 4;      // 4 m-tiles (chunk-local)
    const int nt0 = h * 8;         // 8 n-tiles

    f32x4 acc[2][4] = {};

    auto stage = [&](int buf, int kt) {
        #pragma unroll
        for (int s = 0; s < 6; ++s) {
            int tt = w * 6 + s;
            const __hip_bfloat16* g;
            if (tt < 4)       g = Ah  + ((size_t)(rt0 + tt)      * NKT + kt) * 512;
            else if (tt < 8)  g = Al_ + ((size_t)(rt0 + tt - 4)  * NKT + kt) * 512;
            else if (tt < 16) g = Wh  + ((size_t)(nt0 + tt - 8)  * NKT + kt) * 512;
            else              g = Wl  + ((size_t)(nt0 + tt - 16) * NKT + kt) * 512;
            gload_lds16(g + lane * 8, &L[buf][tt * 512]);
        }
    };

    stage(0, 0);
    int cur = 0;
    __syncthreads();

    for (int kt = 0; kt < NKT; ++kt) {
        if (kt + 1 < NKT) stage(cur ^ 1, kt + 1);   // issue-early prefetch

        const int fb = (lane >> 4) * 128 + (lane & 15) * 8;
        s16x8 ah[2], al4[2], bh[4], bl4[4];
        #pragma unroll
        for (int mm = 0; mm < 2; ++mm) {
            int base = (2 * wm + mm) * 512 + fb;
            ah[mm]  = *reinterpret_cast<const s16x8*>(&L[cur][base]);
            al4[mm] = *reinterpret_cast<const s16x8*>(&L[cur][2048 + base]);
        }
        #pragma unroll
        for (int nnn = 0; nnn < 4; ++nnn) {
            int base = (4 * wn + nnn) * 512 + fb;
            bh[nnn]  = *reinterpret_cast<const s16x8*>(&L[cur][4096 + base]);
            bl4[nnn] = *reinterpret_cast<const s16x8*>(&L[cur][8192 + base]);
        }

        #pragma unroll
        for (int mm = 0; mm < 2; ++mm)
            #pragma unroll
            for (int nnn = 0; nnn < 4; ++nnn) {
                acc[mm][nnn] = __builtin_amdgcn_mfma_f32_16x16x32_bf16(ah[mm],  bh[nnn],  acc[mm][nnn], 0, 0, 0);
                acc[mm][nnn] = __builtin_amdgcn_mfma_f32_16x16x32_bf16(ah[mm],  bl4[nnn], acc[mm][nnn], 0, 0, 0);
                acc[mm][nnn] = __builtin_amdgcn_mfma_f32_16x16x32_bf16(al4[mm], bh[nnn],  acc[mm][nnn], 0, 0, 0);
            }

        __syncthreads();   // reads done + prefetch drained
        cur ^= 1;
    }

    // ---- epilogue: transpose through LDS, coalesced stores with bias ----
    float* T = (float*)&L[0][0];   // 64 x 132 floats (stride-pad vs conflicts)
    #pragma unroll
    for (int mm = 0; mm < 2; ++mm)
        #pragma unroll
        for (int nnn = 0; nnn < 4; ++nnn)
            #pragma unroll
            for (int rr = 0; rr < 4; ++rr) {
                int p = wm * 32 + mm * 16 + (lane >> 4) * 4 + rr;
                int o = wn * 64 + nnn * 16 + (lane & 15);
                T[p * 132 + o] = acc[mm][nnn][rr];
            }
    __syncthreads();

    const int pbase = r_start + mIdx * 64;
    const int ii = pbase >> 9;
    const int jj0 = (pbase >> 3) & 63;
    const int ol = t >> 1, hh = t & 1;
    const int o = n0 + ol;
    const float bo = b[o];
    #pragma unroll
    for (int c = 0; c < 4; ++c) {
        int ni = hh * 4 + c;
        float v[8];
        #pragma unroll
        for (int qq = 0; qq < 8; ++qq) v[qq] = T[(qq * 8 + ni) * 132 + ol] + bo;
        float* dst = out + (size_t)(ni * 256 + o) * 1600 + ii * 64 + jj0;
        *reinterpret_cast<float4*>(dst)     = make_float4(v[0], v[1], v[2], v[3]);
        *reinterpret_cast<float4*>(dst + 4) = make_float4(v[4], v[5], v[6], v[7]);
    }
}

// ---------------------------------------------------------------------------
extern "C" void kernel_launch(void* const* d_in, const int* in_sizes, int n_in,
                              void* d_out, int out_size, void* d_ws, size_t ws_size,
                              hipStream_t stream)
{
    const float* x = (const float*)d_in[0];
    const float* W = (const float*)d_in[1];
    const float* b = (const float*)d_in[2];
    float* out = (float*)d_out;

    char* ws = (char*)d_ws;
    __hip_bfloat16* Wh = (__hip_bfloat16*)ws;
    __hip_bfloat16* Wl = Wh + (size_t)16 * NKT * 512;            // 622,592 elems each
    size_t a_off = (((size_t)16 * NKT * 512 * 2 * 2) + 255) & ~(size_t)255;

    size_t avail = (ws_size > a_off) ? ws_size - a_off : 0;
    long long maxp = (long long)(avail / ((size_t)KPAD * 2 * 2));
    int chunk = (int)((maxp / 128) * 128);
    if (chunk > NPATH) chunk = NPATH;
    if (chunk < 128) chunk = 128;   // assume ws is at least ~4 MB

    __hip_bfloat16* Ah = (__hip_bfloat16*)(ws + a_off);
    __hip_bfloat16* Al_ = Ah + (size_t)chunk * KPAD;

    wconv_kernel<<<dim3(10, 256), 256, 0, stream>>>(W, Wh, Wl);

    for (int r0 = 0; r0 < NPATH; r0 += chunk) {
        int cnt = NPATH - r0;
        if (cnt > chunk) cnt = chunk;
        int nmblk = cnt / 64;
        int nblk = ((nmblk + 7) / 8) * 16;
        sig_kernel<<<dim3(cnt / 16), 256, 0, stream>>>(x, Ah, Al_, r0);
        gemm_kernel<<<dim3(nblk), 256, 0, stream>>>(Ah, Al_, Wh, Wl, b, out, r0, nmblk);
    }
}